// Round 2
// baseline (2243.961 us; speedup 1.0000x reference)
//
#include <hip/hip_runtime.h>
#include <math.h>

#define TS 1024
#define CD 1024
#define NH 16
#define HD 64
#define NL 6
#define NV 8192
#define NB 2
#define MR (NB*TS)   // 2048 rows

typedef __attribute__((ext_vector_type(8))) short s8v;            // 8 bf16
typedef __attribute__((ext_vector_type(4))) float f4v;            // mfma acc
typedef __attribute__((ext_vector_type(4))) unsigned short u4v;   // 4 bf16

__device__ __forceinline__ unsigned short f2bf(float f) {
    unsigned u = __builtin_bit_cast(unsigned, f);
    u += 0x7fffu + ((u >> 16) & 1u);               // RNE
    return (unsigned short)(u >> 16);
}
__device__ __forceinline__ float bf2f(unsigned short h) {
    return __builtin_bit_cast(float, ((unsigned)h) << 16);
}
// XOR-swizzled LDS byte offset: row stride 128B (64 bf16), 8 x 16B slots
__device__ __forceinline__ int swz(int r, int s) {
    return r * 128 + ((s ^ (r & 7)) << 4);
}

// ---------------------------------------------------------------------------
// Generic bf16 MFMA GEMM, out[m][n] = sum_k A[m][k] * W[n][k]  (B^T layout)
// EPI: 0 = f32 out (+bias if non-null)          [head]
//      2 = QKV scatter (q,k row-major; v transposed [B,H,D,T])
//      3 = S = scale*acc -> bf16, batched by z, causal tile-skip
//      4 = PV scatter -> y[b,t, h*64+d], batched by z=bh (global z = z+zoff)
//      5 = x[m][n] += acc + bias  (residual, in-place f32)
//      6 = bf16 out = gelu(acc + bias)  (exact erf)
// ---------------------------------------------------------------------------
template<int WMW, int WNW, bool BBF, int EPI>
__global__ __launch_bounds__(WMW*WNW*64)
void gemm_bt(const unsigned short* __restrict__ A,
             const void* B0, const void* B1v, const void* B2v,
             const float* __restrict__ bias0, const float* __restrict__ bias1,
             const float* __restrict__ bias2,
             void* out0, void* out1, void* out2,
             int N, int K, int lda, int ldb,
             long sA, long sB, long sO, float scale, int zoff)
{
    constexpr int BM = WMW*64, BN = WNW*64, NT = WMW*WNW*64;
    __shared__ __attribute__((aligned(16))) char lds[(BM+BN)*128];
    char* As = lds;
    char* Bs = lds + BM*128;

    const int n0 = blockIdx.x * BN;
    const int m0 = blockIdx.y * BM;
    const int z  = blockIdx.z;
    if (EPI == 3) { if (n0 > m0 + BM - 1) return; }   // fully-masked tile

    const unsigned short* Ab = A + (size_t)z * sA;
    const void* Bsel = B0;
    int nB0 = n0;
    if (EPI == 2) {                 // QKV: pick Wq/Wk/Wv by section of n
        int sec = n0 >> 10; nB0 = n0 & 1023;
        if (sec == 1) Bsel = B1v; else if (sec == 2) Bsel = B2v;
    }
    const unsigned short* Bb = (const unsigned short*)Bsel + (BBF ? (size_t)z*sB : 0);
    const float* Bf = (const float*)Bsel;

    const int tid  = threadIdx.x;
    const int wave = tid >> 6, lane = tid & 63;
    const int wr = wave / WNW, wc = wave % WNW;
    const int lr = lane & 15, lk = lane >> 4;

    f4v acc[4][4];
    #pragma unroll
    for (int i = 0; i < 4; ++i)
        #pragma unroll
        for (int j = 0; j < 4; ++j) acc[i][j] = 0;

    constexpr int AIT = (BM*8)/NT, BIT = (BN*8)/NT;

    for (int kt = 0; kt < K; kt += 64) {
        #pragma unroll
        for (int i = 0; i < AIT; ++i) {
            int u = tid + i*NT, r = u >> 3, s = u & 7;
            s8v v = *(const s8v*)(Ab + (size_t)(m0 + r)*lda + kt + s*8);
            *(s8v*)(As + swz(r, s)) = v;
        }
        #pragma unroll
        for (int i = 0; i < BIT; ++i) {
            int u = tid + i*NT, r = u >> 3, s = u & 7;
            s8v v;
            if (BBF) {
                v = *(const s8v*)(Bb + (size_t)(nB0 + r)*ldb + kt + s*8);
            } else {
                const float* p = Bf + (size_t)(nB0 + r)*ldb + kt + s*8;
                float4 f0 = *(const float4*)p;
                float4 f1 = *(const float4*)(p + 4);
                v[0] = (short)f2bf(f0.x); v[1] = (short)f2bf(f0.y);
                v[2] = (short)f2bf(f0.z); v[3] = (short)f2bf(f0.w);
                v[4] = (short)f2bf(f1.x); v[5] = (short)f2bf(f1.y);
                v[6] = (short)f2bf(f1.z); v[7] = (short)f2bf(f1.w);
            }
            *(s8v*)(Bs + swz(r, s)) = v;
        }
        __syncthreads();

        s8v af[4][2], bfr[4][2];
        #pragma unroll
        for (int mi = 0; mi < 4; ++mi)
            #pragma unroll
            for (int kk = 0; kk < 2; ++kk) {
                int R = wr*64 + mi*16 + lr;
                af[mi][kk] = *(const s8v*)(As + swz(R, kk*4 + lk));
            }
        #pragma unroll
        for (int nj = 0; nj < 4; ++nj)
            #pragma unroll
            for (int kk = 0; kk < 2; ++kk) {
                int R = wc*64 + nj*16 + lr;
                bfr[nj][kk] = *(const s8v*)(Bs + swz(R, kk*4 + lk));
            }
        #pragma unroll
        for (int mi = 0; mi < 4; ++mi)
            #pragma unroll
            for (int nj = 0; nj < 4; ++nj) {
                acc[mi][nj] = __builtin_amdgcn_mfma_f32_16x16x32_bf16(af[mi][0], bfr[nj][0], acc[mi][nj], 0, 0, 0);
                acc[mi][nj] = __builtin_amdgcn_mfma_f32_16x16x32_bf16(af[mi][1], bfr[nj][1], acc[mi][nj], 0, 0, 0);
            }
        __syncthreads();
    }

    // epilogue: C/D frag layout col = lane&15, row = (lane>>4)*4 + ri
    #pragma unroll
    for (int mi = 0; mi < 4; ++mi)
    #pragma unroll
    for (int nj = 0; nj < 4; ++nj) {
        int gm_b = m0 + wr*64 + mi*16 + lk*4;
        int gn   = n0 + wc*64 + nj*16 + lr;
        #pragma unroll
        for (int ri = 0; ri < 4; ++ri) {
            int gm = gm_b + ri;
            float v = acc[mi][nj][ri];
            if (EPI == 0) {
                if (bias0) v += bias0[gn];
                ((float*)out0)[(size_t)gm * N + gn] = v;
            } else if (EPI == 2) {
                int sec = gn >> 10, nn = gn & 1023;
                int hh = nn >> 6, dd = nn & 63;
                int bb = gm >> 10, tt = gm & 1023;
                const float* bp_ = (sec == 0) ? bias0 : (sec == 1 ? bias1 : bias2);
                unsigned short bvv = f2bf(v + bp_[nn]);
                size_t bh = (size_t)bb * NH + hh;
                if (sec == 0)      ((unsigned short*)out0)[(bh*TS + tt)*HD + dd] = bvv;
                else if (sec == 1) ((unsigned short*)out1)[(bh*TS + tt)*HD + dd] = bvv;
                else               ((unsigned short*)out2)[(bh*HD + dd)*TS + tt] = bvv;
            } else if (EPI == 3) {
                ((unsigned short*)out0)[(size_t)z*sO + (size_t)gm*N + gn] = f2bf(v * scale);
            } else if (EPI == 4) {
                int zg = z + zoff;
                int bb = zg >> 4, hh = zg & 15;
                ((unsigned short*)out0)[((size_t)(bb*TS + gm))*CD + hh*HD + gn] = f2bf(v);
            } else if (EPI == 5) {
                size_t o = (size_t)gm * N + gn;
                ((float*)out0)[o] += v + bias0[gn];
            } else if (EPI == 6) {
                float t = v + bias0[gn];
                float g = 0.5f * t * (1.0f + erff(t * 0.70710678118654752f));
                ((unsigned short*)out0)[(size_t)gm * N + gn] = f2bf(g);
            }
        }
    }
}

// ---------------------------------------------------------------------------
__global__ __launch_bounds__(256)
void ln_kernel(const float* __restrict__ x, const float* __restrict__ w,
               const float* __restrict__ b, unsigned short* __restrict__ out)
{
    __shared__ float red[8];
    const int row = blockIdx.x, tid = threadIdx.x;
    const float* xr = x + (size_t)row * CD;
    float4 v = ((const float4*)xr)[tid];
    float s  = v.x + v.y + v.z + v.w;
    float s2 = v.x*v.x + v.y*v.y + v.z*v.z + v.w*v.w;
    #pragma unroll
    for (int m = 32; m; m >>= 1) { s += __shfl_xor(s, m); s2 += __shfl_xor(s2, m); }
    if ((tid & 63) == 0) { red[tid >> 6] = s; red[4 + (tid >> 6)] = s2; }
    __syncthreads();
    s  = red[0] + red[1] + red[2] + red[3];
    s2 = red[4] + red[5] + red[6] + red[7];
    float mean = s * (1.0f / CD);
    float var  = s2 * (1.0f / CD) - mean * mean;
    float rstd = rsqrtf(var + 1e-5f);
    float4 wv = ((const float4*)w)[tid];
    float4 bv = ((const float4*)b)[tid];
    u4v o;
    o[0] = f2bf((v.x - mean) * rstd * wv.x + bv.x);
    o[1] = f2bf((v.y - mean) * rstd * wv.y + bv.y);
    o[2] = f2bf((v.z - mean) * rstd * wv.z + bv.z);
    o[3] = f2bf((v.w - mean) * rstd * wv.w + bv.w);
    *(u4v*)(out + (size_t)row * CD + tid * 4) = o;
}

// wave-per-row causal softmax, in-place on bf16 S
__global__ __launch_bounds__(256)
void softmax_kernel(unsigned short* __restrict__ S)
{
    const int gw = blockIdx.x * 4 + (threadIdx.x >> 6);   // local row: zl*1024+q
    const int lane = threadIdx.x & 63;
    const int q = gw & (TS - 1);
    unsigned short* row = S + (size_t)gw * TS;
    s8v v0 = *(const s8v*)(row + lane * 16);
    s8v v1 = *(const s8v*)(row + lane * 16 + 8);
    float f[16];
    float mx = -3e38f;
    #pragma unroll
    for (int i = 0; i < 16; ++i) {
        int k = lane * 16 + i;
        unsigned short hv = (unsigned short)(i < 8 ? v0[i] : v1[i - 8]);
        f[i] = (k <= q) ? bf2f(hv) : -3e38f;
        mx = fmaxf(mx, f[i]);
    }
    #pragma unroll
    for (int m = 32; m; m >>= 1) mx = fmaxf(mx, __shfl_xor(mx, m));
    float sum = 0.f;
    #pragma unroll
    for (int i = 0; i < 16; ++i) {
        int k = lane * 16 + i;
        float e = (k <= q) ? __expf(f[i] - mx) : 0.f;
        f[i] = e; sum += e;
    }
    #pragma unroll
    for (int m = 32; m; m >>= 1) sum += __shfl_xor(sum, m);
    float r = 1.0f / sum;
    #pragma unroll
    for (int i = 0; i < 8; ++i) { v0[i] = (short)f2bf(f[i] * r); v1[i] = (short)f2bf(f[i+8] * r); }
    *(s8v*)(row + lane * 16) = v0;
    *(s8v*)(row + lane * 16 + 8) = v1;
}

__global__ __launch_bounds__(256)
void embed_kernel(const int* __restrict__ idx, const float* __restrict__ tok,
                  const float* __restrict__ pos, const float* __restrict__ ab,
                  float* __restrict__ x)
{
    const int row = blockIdx.x;            // b*T + t
    const int b = row >> 10, t = row & 1023;
    const int i0 = idx[b*3*TS + t];
    const int i1 = idx[b*3*TS + TS + t];
    const int i2 = idx[b*3*TS + 2*TS + t];
    float4 tv = ((const float4*)(tok + (size_t)i0*CD))[threadIdx.x];
    float4 pv = ((const float4*)(pos + (size_t)i1*CD))[threadIdx.x];
    float4 av = ((const float4*)(ab  + (size_t)i2*CD))[threadIdx.x];
    float4 o; o.x = tv.x+pv.x+av.x; o.y = tv.y+pv.y+av.y;
    o.z = tv.z+pv.z+av.z; o.w = tv.w+pv.w+av.w;
    ((float4*)(x + (size_t)row*CD))[threadIdx.x] = o;
}

// ---------------------------------------------------------------------------
extern "C" void kernel_launch(void* const* d_in, const int* in_sizes, int n_in,
                              void* d_out, int out_size, void* d_ws, size_t ws_size,
                              hipStream_t stream)
{
    const int*   idx   = (const int*)  d_in[0];
    const float* tok   = (const float*)d_in[1];
    const float* pos   = (const float*)d_in[2];
    const float* ab    = (const float*)d_in[3];
    const float* lnfw  = (const float*)d_in[4];
    const float* lnfb  = (const float*)d_in[5];
    const float* headw = (const float*)d_in[6];
    const float* ln1w  = (const float*)d_in[7];
    const float* ln1b  = (const float*)d_in[8];
    const float* Wq    = (const float*)d_in[9];
    const float* bq    = (const float*)d_in[10];
    const float* Wk    = (const float*)d_in[11];
    const float* bk    = (const float*)d_in[12];
    const float* Wv    = (const float*)d_in[13];
    const float* bv    = (const float*)d_in[14];
    const float* Wp    = (const float*)d_in[15];
    const float* bp    = (const float*)d_in[16];
    const float* ln2w  = (const float*)d_in[17];
    const float* ln2b  = (const float*)d_in[18];
    const float* W1    = (const float*)d_in[19];
    const float* b1    = (const float*)d_in[20];
    const float* W2    = (const float*)d_in[21];
    const float* b2    = (const float*)d_in[22];

    char* ws = (char*)d_ws;
    float*          x   = (float*)(ws);                          //  8 MB f32 [2048,1024]
    unsigned short* h   = (unsigned short*)(ws + (8u<<20));      //  4 MB bf16 LN out
    unsigned short* qb  = (unsigned short*)(ws + (12u<<20));     //  4 MB [B,H,T,D]
    unsigned short* kb  = (unsigned short*)(ws + (16u<<20));     //  4 MB [B,H,T,D]
    unsigned short* vtb = (unsigned short*)(ws + (20u<<20));     //  4 MB [B,H,D,T]
    unsigned short* yb  = (unsigned short*)(ws + (24u<<20));     //  4 MB [2048,1024]
    unsigned short* Sb  = (unsigned short*)(ws + (28u<<20));     // up to 64 MB S chunk
    unsigned short* mid = (unsigned short*)(ws + (28u<<20));     // 16 MB MLP mid (overlaps Sb)

    // attention z-chunking based on available workspace (constant across calls)
    int zchunk = 32;                                  // 64 MB S  -> 92 MB total
    if (ws_size < (28u<<20) + (64u<<20)) zchunk = 16; // 32 MB S  -> 60 MB total
    if (ws_size < (28u<<20) + (32u<<20)) zchunk = 8;  // 16 MB S  -> 44 MB total

    embed_kernel<<<MR, 256, 0, stream>>>(idx, tok, pos, ab, x);

    for (int l = 0; l < NL; ++l) {
        size_t wo = (size_t)l * CD * CD;
        ln_kernel<<<MR, 256, 0, stream>>>(x, ln1w + l*CD, ln1b + l*CD, h);
        // QKV fused: N=3072 across {Wq,Wk,Wv}
        gemm_bt<2,2,false,2><<<dim3(24,16,1), 256, 0, stream>>>(
            h, Wq + wo, Wk + wo, Wv + wo,
            bq + l*CD, bk + l*CD, bv + l*CD,
            qb, kb, vtb,
            3072, 1024, CD, CD, 0, 0, 0, 1.f, 0);
        for (int zc = 0; zc < 32; zc += zchunk) {
            // S = QK^T * 1/8, batched over zchunk (b,h)
            gemm_bt<2,2,true,3><<<dim3(8,8,zchunk), 256, 0, stream>>>(
                qb + (size_t)zc*TS*HD, kb + (size_t)zc*TS*HD, nullptr, nullptr,
                nullptr, nullptr, nullptr,
                Sb, nullptr, nullptr,
                1024, 64, HD, HD, (long)TS*HD, (long)TS*HD, (long)TS*TS, 0.125f, 0);
            softmax_kernel<<<(zchunk*TS)/4, 256, 0, stream>>>(Sb);
            // y = P @ V  (V pre-transposed -> B^T form), BN=64
            gemm_bt<2,1,true,4><<<dim3(1,8,zchunk), 128, 0, stream>>>(
                Sb, vtb + (size_t)zc*HD*TS, nullptr, nullptr,
                nullptr, nullptr, nullptr,
                yb, nullptr, nullptr,
                64, 1024, TS, TS, (long)TS*TS, (long)HD*TS, 0, 1.f, zc);
        }
        // x += y @ Wp^T + bp
        gemm_bt<2,2,false,5><<<dim3(8,16,1), 256, 0, stream>>>(
            yb, Wp + wo, nullptr, nullptr,
            bp + l*CD, nullptr, nullptr,
            x, nullptr, nullptr,
            1024, 1024, CD, CD, 0, 0, 0, 1.f, 0);
        ln_kernel<<<MR, 256, 0, stream>>>(x, ln2w + l*CD, ln2b + l*CD, h);
        // mid = gelu(h @ W1^T + b1)
        gemm_bt<2,2,false,6><<<dim3(32,16,1), 256, 0, stream>>>(
            h, W1 + (size_t)l*4*CD*CD, nullptr, nullptr,
            b1 + (size_t)l*4*CD, nullptr, nullptr,
            mid, nullptr, nullptr,
            4096, 1024, CD, CD, 0, 0, 0, 1.f, 0);
        // x += mid @ W2^T + b2
        gemm_bt<2,2,false,5><<<dim3(8,16,1), 256, 0, stream>>>(
            mid, W2 + (size_t)l*CD*4*CD, nullptr, nullptr,
            b2 + l*CD, nullptr, nullptr,
            x, nullptr, nullptr,
            1024, 4096, 4*CD, 4*CD, 0, 0, 0, 1.f, 0);
    }
    ln_kernel<<<MR, 256, 0, stream>>>(x, lnfw, lnfb, h);
    // logits = h @ head^T (no bias), f32 out
    gemm_bt<2,2,false,0><<<dim3(64,16,1), 256, 0, stream>>>(
        h, headw, nullptr, nullptr, nullptr, nullptr, nullptr,
        (float*)d_out, nullptr, nullptr,
        8192, 1024, CD, CD, 0, 0, 0, 1.f, 0);
}